// Round 1
// baseline (4485.259 us; speedup 1.0000x reference)
//
#include <hip/hip_runtime.h>

typedef float f32x4 __attribute__((ext_vector_type(4)));

#define HD 128
#define TM 64

__device__ __forceinline__ float prelu_f(float x, float a) {
  return x > 0.f ? x : a * x;
}

// out = concat(node_scalar, node_vector)
__global__ __launch_bounds__(256) void init_out_kernel(
    const f32x4* __restrict__ ns, const f32x4* __restrict__ nv,
    f32x4* __restrict__ out, int n_ns4, int n_nv4)
{
  int total = n_ns4 + n_nv4;
  for (int i = blockIdx.x * 256 + threadIdx.x; i < total; i += gridDim.x * 256)
    out[i] = (i < n_ns4) ? ns[i] : nv[i - n_ns4];
}

// scalar-branch MLP: out[M,384] = prelu(prelu(A@w1+b1)@w2+b2)
__global__ __launch_bounds__(256) void node_mlp_kernel(
    const float* __restrict__ A,
    const float* __restrict__ w1, const float* __restrict__ b1, const float* __restrict__ a1p,
    const float* __restrict__ w2, const float* __restrict__ b2, const float* __restrict__ a2p,
    float* __restrict__ out, int M)
{
  __shared__ float A_lds[TM][HD];
  __shared__ float h_lds[TM][HD];
  const int t = threadIdx.x;
  const int tx = t & 31, ty = t >> 5;
  const int c4 = tx * 4;
  const int m0 = blockIdx.x * TM;
  const float a1 = a1p[0], a2 = a2p[0];

  // stage A tile
  for (int idx = t; idx < TM * HD / 4; idx += 256) {
    int r = idx >> 5;
    int cc = (idx & 31) * 4;
    f32x4 v = {0.f, 0.f, 0.f, 0.f};
    if (m0 + r < M) v = *(const f32x4*)&A[(size_t)(m0 + r) * HD + cc];
    *(f32x4*)&A_lds[r][cc] = v;
  }
  __syncthreads();

  float acc[8][4];
  // ---- layer 1: h = prelu(A@w1+b1) ----
  {
    f32x4 bv = *(const f32x4*)&b1[c4];
    #pragma unroll
    for (int rr = 0; rr < 8; rr++)
      #pragma unroll
      for (int cc = 0; cc < 4; cc++) acc[rr][cc] = bv[cc];

    for (int kg = 0; kg < HD / 4; kg++) {
      const int k = kg * 4;
      f32x4 wv[4];
      #pragma unroll
      for (int kk = 0; kk < 4; kk++) wv[kk] = *(const f32x4*)&w1[(size_t)(k + kk) * HD + c4];
      #pragma unroll
      for (int rr = 0; rr < 8; rr++) {
        f32x4 av = *(const f32x4*)&A_lds[ty + 8 * rr][k];
        #pragma unroll
        for (int cc = 0; cc < 4; cc++)
          #pragma unroll
          for (int kk = 0; kk < 4; kk++)
            acc[rr][cc] += av[kk] * wv[kk][cc];
      }
    }
    #pragma unroll
    for (int rr = 0; rr < 8; rr++) {
      f32x4 hv;
      #pragma unroll
      for (int cc = 0; cc < 4; cc++) hv[cc] = prelu_f(acc[rr][cc], a1);
      *(f32x4*)&h_lds[ty + 8 * rr][c4] = hv;
    }
  }
  __syncthreads();

  // ---- layer 2: out = prelu(h@w2+b2), 3 column-planes of 128 ----
  for (int m = 0; m < 3; m++) {
    f32x4 bv = *(const f32x4*)&b2[m * HD + c4];
    #pragma unroll
    for (int rr = 0; rr < 8; rr++)
      #pragma unroll
      for (int cc = 0; cc < 4; cc++) acc[rr][cc] = bv[cc];

    for (int kg = 0; kg < HD / 4; kg++) {
      const int k = kg * 4;
      f32x4 wv[4];
      #pragma unroll
      for (int kk = 0; kk < 4; kk++)
        wv[kk] = *(const f32x4*)&w2[(size_t)(k + kk) * 384 + m * HD + c4];
      #pragma unroll
      for (int rr = 0; rr < 8; rr++) {
        f32x4 av = *(const f32x4*)&h_lds[ty + 8 * rr][k];
        #pragma unroll
        for (int cc = 0; cc < 4; cc++)
          #pragma unroll
          for (int kk = 0; kk < 4; kk++)
            acc[rr][cc] += av[kk] * wv[kk][cc];
      }
    }
    #pragma unroll
    for (int rr = 0; rr < 8; rr++) {
      int r = ty + 8 * rr;
      if (m0 + r < M) {
        f32x4 ov;
        #pragma unroll
        for (int cc = 0; cc < 4; cc++) ov[cc] = prelu_f(acc[rr][cc], a2);
        *(f32x4*)&out[(size_t)(m0 + r) * 384 + m * HD + c4] = ov;
      }
    }
  }
}

// filter MLP + gather + gate + scatter-add
__global__ __launch_bounds__(256) void edge_kernel(
    const float* __restrict__ so,      // [N,384] scalar_out
    const float* __restrict__ nv,      // [N,3,128]
    const int*   __restrict__ edge,    // [E,2]  (dst, src)
    const float* __restrict__ diff,    // [E,3]
    const float* __restrict__ dist,    // [E]
    const float* __restrict__ rbf,     // [E,20]
    const float* __restrict__ w1,      // [20,128]
    const float* __restrict__ b1, const float* __restrict__ a1p,
    const float* __restrict__ w2,      // [128,384]
    const float* __restrict__ b2, const float* __restrict__ a2p,
    float* __restrict__ out_s,         // [N,128]
    float* __restrict__ out_v,         // [N,3,128]
    int E)
{
  __shared__ float R_lds[TM][20];
  __shared__ float h_lds[TM][HD];
  __shared__ int   src_l[TM], dst_l[TM];
  __shared__ float unit_l[TM][3];

  const int t = threadIdx.x;
  const int tx = t & 31, ty = t >> 5;
  const int c4 = tx * 4;
  const int e0 = blockIdx.x * TM;
  const float a1 = a1p[0], a2 = a2p[0];

  // stage rbf tile + edge metadata
  for (int idx = t; idx < TM * 20; idx += 256) {
    int r = idx / 20, k = idx - r * 20;
    int e = e0 + r;
    R_lds[r][k] = (e < E) ? rbf[(size_t)e * 20 + k] : 0.f;
  }
  if (t < TM) {
    int e = min(e0 + t, E - 1);
    src_l[t] = edge[(size_t)e * 2 + 1];
    dst_l[t] = edge[(size_t)e * 2 + 0];
    float inv = 1.f / dist[e];
    unit_l[t][0] = diff[(size_t)e * 3 + 0] * inv;
    unit_l[t][1] = diff[(size_t)e * 3 + 1] * inv;
    unit_l[t][2] = diff[(size_t)e * 3 + 2] * inv;
  }
  __syncthreads();

  // ---- filter layer 1 (K=20) ----
  {
    float acc[8][4];
    f32x4 bv = *(const f32x4*)&b1[c4];
    #pragma unroll
    for (int rr = 0; rr < 8; rr++)
      #pragma unroll
      for (int cc = 0; cc < 4; cc++) acc[rr][cc] = bv[cc];

    for (int k = 0; k < 20; k++) {
      f32x4 wv = *(const f32x4*)&w1[(size_t)k * HD + c4];
      #pragma unroll
      for (int rr = 0; rr < 8; rr++) {
        float av = R_lds[ty + 8 * rr][k];
        #pragma unroll
        for (int cc = 0; cc < 4; cc++) acc[rr][cc] += av * wv[cc];
      }
    }
    #pragma unroll
    for (int rr = 0; rr < 8; rr++) {
      f32x4 hv;
      #pragma unroll
      for (int cc = 0; cc < 4; cc++) hv[cc] = prelu_f(acc[rr][cc], a1);
      *(f32x4*)&h_lds[ty + 8 * rr][c4] = hv;
    }
  }
  __syncthreads();

  // ---- filter layer 2: 3 gate planes held simultaneously ----
  float acc2[3][8][4];
  #pragma unroll
  for (int m = 0; m < 3; m++) {
    f32x4 bv = *(const f32x4*)&b2[m * HD + c4];
    #pragma unroll
    for (int rr = 0; rr < 8; rr++)
      #pragma unroll
      for (int cc = 0; cc < 4; cc++) acc2[m][rr][cc] = bv[cc];
  }
  for (int kg = 0; kg < HD / 4; kg++) {
    const int k = kg * 4;
    f32x4 av[8];
    #pragma unroll
    for (int rr = 0; rr < 8; rr++) av[rr] = *(const f32x4*)&h_lds[ty + 8 * rr][k];
    #pragma unroll
    for (int m = 0; m < 3; m++) {
      f32x4 wv[4];
      #pragma unroll
      for (int kk = 0; kk < 4; kk++)
        wv[kk] = *(const f32x4*)&w2[(size_t)(k + kk) * 384 + m * HD + c4];
      #pragma unroll
      for (int rr = 0; rr < 8; rr++)
        #pragma unroll
        for (int cc = 0; cc < 4; cc++)
          #pragma unroll
          for (int kk = 0; kk < 4; kk++)
            acc2[m][rr][cc] += av[rr][kk] * wv[kk][cc];
    }
  }

  // ---- epilogue: gather, gate, scatter-add ----
  #pragma unroll
  for (int rr = 0; rr < 8; rr++) {
    const int r = ty + 8 * rr;
    const int e = e0 + r;
    if (e >= E) continue;
    const int src = src_l[r], dst = dst_l[r];
    const float u0 = unit_l[r][0], u1 = unit_l[r][1], u2 = unit_l[r][2];
    const size_t sb = (size_t)src * 384;
    f32x4 s0 = *(const f32x4*)&so[sb + c4];
    f32x4 s1 = *(const f32x4*)&so[sb + HD + c4];
    f32x4 s2 = *(const f32x4*)&so[sb + 2 * HD + c4];
    f32x4 gv, ms, ge;
    #pragma unroll
    for (int cc = 0; cc < 4; cc++) {
      gv[cc] = prelu_f(acc2[0][rr][cc], a2) * s0[cc];
      ms[cc] = prelu_f(acc2[1][rr][cc], a2) * s1[cc];
      ge[cc] = prelu_f(acc2[2][rr][cc], a2) * s2[cc];
    }
    float* osp = &out_s[(size_t)dst * HD + c4];
    #pragma unroll
    for (int cc = 0; cc < 4; cc++) atomicAdd(osp + cc, ms[cc]);
    #pragma unroll
    for (int d = 0; d < 3; d++) {
      f32x4 nvv = *(const f32x4*)&nv[((size_t)src * 3 + d) * HD + c4];
      const float ud = (d == 0) ? u0 : (d == 1) ? u1 : u2;
      float* ovp = &out_v[((size_t)dst * 3 + d) * HD + c4];
      #pragma unroll
      for (int cc = 0; cc < 4; cc++)
        atomicAdd(ovp + cc, nvv[cc] * gv[cc] + ud * ge[cc]);
    }
  }
}

extern "C" void kernel_launch(void* const* d_in, const int* in_sizes, int n_in,
                              void* d_out, int out_size, void* d_ws, size_t ws_size,
                              hipStream_t stream)
{
  const float* node_scalar = (const float*)d_in[0];
  const float* node_vector = (const float*)d_in[1];
  const int*   che_edge = (const int*)d_in[2];
  const float* che_diff = (const float*)d_in[3];
  const float* che_dist = (const float*)d_in[4];
  const float* che_rbf  = (const float*)d_in[5];
  const int*   vdw_edge = (const int*)d_in[6];
  const float* vdw_diff = (const float*)d_in[7];
  const float* vdw_dist = (const float*)d_in[8];
  const float* vdw_rbf  = (const float*)d_in[9];
  const float* che_s_w1 = (const float*)d_in[10];
  const float* che_s_b1 = (const float*)d_in[11];
  const float* che_s_a1 = (const float*)d_in[12];
  const float* che_s_w2 = (const float*)d_in[13];
  const float* che_s_b2 = (const float*)d_in[14];
  const float* che_s_a2 = (const float*)d_in[15];
  const float* che_f_w1 = (const float*)d_in[16];
  const float* che_f_b1 = (const float*)d_in[17];
  const float* che_f_a1 = (const float*)d_in[18];
  const float* che_f_w2 = (const float*)d_in[19];
  const float* che_f_b2 = (const float*)d_in[20];
  const float* che_f_a2 = (const float*)d_in[21];
  const float* vdw_s_w1 = (const float*)d_in[22];
  const float* vdw_s_b1 = (const float*)d_in[23];
  const float* vdw_s_a1 = (const float*)d_in[24];
  const float* vdw_s_w2 = (const float*)d_in[25];
  const float* vdw_s_b2 = (const float*)d_in[26];
  const float* vdw_s_a2 = (const float*)d_in[27];
  const float* vdw_f_w1 = (const float*)d_in[28];
  const float* vdw_f_b1 = (const float*)d_in[29];
  const float* vdw_f_a1 = (const float*)d_in[30];
  const float* vdw_f_w2 = (const float*)d_in[31];
  const float* vdw_f_b2 = (const float*)d_in[32];
  const float* vdw_f_a2 = (const float*)d_in[33];

  const int N = in_sizes[0] / HD;
  const int E_che = in_sizes[4];
  const int E_vdw = in_sizes[8];

  float* so    = (float*)d_ws;              // [N,384] scalar_out scratch (reused per branch)
  float* out_s = (float*)d_out;             // [N,128]
  float* out_v = out_s + (size_t)N * HD;    // [N,3,128]

  const int n_ns4 = N * HD / 4;
  const int n_nv4 = N * 3 * HD / 4;
  init_out_kernel<<<2048, 256, 0, stream>>>(
      (const f32x4*)node_scalar, (const f32x4*)node_vector, (f32x4*)d_out, n_ns4, n_nv4);

  // che branch
  node_mlp_kernel<<<(N + TM - 1) / TM, 256, 0, stream>>>(
      node_scalar, che_s_w1, che_s_b1, che_s_a1, che_s_w2, che_s_b2, che_s_a2, so, N);
  edge_kernel<<<(E_che + TM - 1) / TM, 256, 0, stream>>>(
      so, node_vector, che_edge, che_diff, che_dist, che_rbf,
      che_f_w1, che_f_b1, che_f_a1, che_f_w2, che_f_b2, che_f_a2,
      out_s, out_v, E_che);

  // vdw branch (reuses so)
  node_mlp_kernel<<<(N + TM - 1) / TM, 256, 0, stream>>>(
      node_scalar, vdw_s_w1, vdw_s_b1, vdw_s_a1, vdw_s_w2, vdw_s_b2, vdw_s_a2, so, N);
  edge_kernel<<<(E_vdw + TM - 1) / TM, 256, 0, stream>>>(
      so, node_vector, vdw_edge, vdw_diff, vdw_dist, vdw_rbf,
      vdw_f_w1, vdw_f_b1, vdw_f_a1, vdw_f_w2, vdw_f_b2, vdw_f_a2,
      out_s, out_v, E_vdw);
}

// Round 2
// 1827.133 us; speedup vs baseline: 2.4548x; 2.4548x over previous
//
#include <hip/hip_runtime.h>

typedef float f32x4 __attribute__((ext_vector_type(4)));

#define HD 128
#define TM 64

__device__ __forceinline__ float prelu_f(float x, float a) {
  return x > 0.f ? x : a * x;
}

__device__ __forceinline__ unsigned short f2bf(float x) {
  union { float f; unsigned u; } a; a.f = x;
  unsigned r = a.u + 0x7fffu + ((a.u >> 16) & 1u);
  return (unsigned short)(r >> 16);
}
__device__ __forceinline__ float bf2f(unsigned short u) {
  union { unsigned u; float f; } a; a.u = ((unsigned)u) << 16;
  return a.f;
}

// out = concat(node_scalar, node_vector)
__global__ __launch_bounds__(256) void init_out_kernel(
    const f32x4* __restrict__ ns, const f32x4* __restrict__ nv,
    f32x4* __restrict__ out, int n_ns4, int n_nv4)
{
  int total = n_ns4 + n_nv4;
  for (int i = blockIdx.x * 256 + threadIdx.x; i < total; i += gridDim.x * 256)
    out[i] = (i < n_ns4) ? ns[i] : nv[i - n_ns4];
}

// scalar-branch MLP: out[M,384] = prelu(prelu(A@w1+b1)@w2+b2)
__global__ __launch_bounds__(256) void node_mlp_kernel(
    const float* __restrict__ A,
    const float* __restrict__ w1, const float* __restrict__ b1, const float* __restrict__ a1p,
    const float* __restrict__ w2, const float* __restrict__ b2, const float* __restrict__ a2p,
    float* __restrict__ out, int M)
{
  __shared__ float A_lds[TM][HD];
  __shared__ float h_lds[TM][HD];
  const int t = threadIdx.x;
  const int tx = t & 31, ty = t >> 5;
  const int c4 = tx * 4;
  const int m0 = blockIdx.x * TM;
  const float a1 = a1p[0], a2 = a2p[0];

  for (int idx = t; idx < TM * HD / 4; idx += 256) {
    int r = idx >> 5;
    int cc = (idx & 31) * 4;
    f32x4 v = {0.f, 0.f, 0.f, 0.f};
    if (m0 + r < M) v = *(const f32x4*)&A[(size_t)(m0 + r) * HD + cc];
    *(f32x4*)&A_lds[r][cc] = v;
  }
  __syncthreads();

  float acc[8][4];
  {
    f32x4 bv = *(const f32x4*)&b1[c4];
    #pragma unroll
    for (int rr = 0; rr < 8; rr++)
      #pragma unroll
      for (int cc = 0; cc < 4; cc++) acc[rr][cc] = bv[cc];

    for (int kg = 0; kg < HD / 4; kg++) {
      const int k = kg * 4;
      f32x4 wv[4];
      #pragma unroll
      for (int kk = 0; kk < 4; kk++) wv[kk] = *(const f32x4*)&w1[(size_t)(k + kk) * HD + c4];
      #pragma unroll
      for (int rr = 0; rr < 8; rr++) {
        f32x4 av = *(const f32x4*)&A_lds[ty + 8 * rr][k];
        #pragma unroll
        for (int cc = 0; cc < 4; cc++)
          #pragma unroll
          for (int kk = 0; kk < 4; kk++)
            acc[rr][cc] += av[kk] * wv[kk][cc];
      }
    }
    #pragma unroll
    for (int rr = 0; rr < 8; rr++) {
      f32x4 hv;
      #pragma unroll
      for (int cc = 0; cc < 4; cc++) hv[cc] = prelu_f(acc[rr][cc], a1);
      *(f32x4*)&h_lds[ty + 8 * rr][c4] = hv;
    }
  }
  __syncthreads();

  for (int m = 0; m < 3; m++) {
    f32x4 bv = *(const f32x4*)&b2[m * HD + c4];
    #pragma unroll
    for (int rr = 0; rr < 8; rr++)
      #pragma unroll
      for (int cc = 0; cc < 4; cc++) acc[rr][cc] = bv[cc];

    for (int kg = 0; kg < HD / 4; kg++) {
      const int k = kg * 4;
      f32x4 wv[4];
      #pragma unroll
      for (int kk = 0; kk < 4; kk++)
        wv[kk] = *(const f32x4*)&w2[(size_t)(k + kk) * 384 + m * HD + c4];
      #pragma unroll
      for (int rr = 0; rr < 8; rr++) {
        f32x4 av = *(const f32x4*)&h_lds[ty + 8 * rr][k];
        #pragma unroll
        for (int cc = 0; cc < 4; cc++)
          #pragma unroll
          for (int kk = 0; kk < 4; kk++)
            acc[rr][cc] += av[kk] * wv[kk][cc];
      }
    }
    #pragma unroll
    for (int rr = 0; rr < 8; rr++) {
      int r = ty + 8 * rr;
      if (m0 + r < M) {
        f32x4 ov;
        #pragma unroll
        for (int cc = 0; cc < 4; cc++) ov[cc] = prelu_f(acc[rr][cc], a2);
        *(f32x4*)&out[(size_t)(m0 + r) * 384 + m * HD + c4] = ov;
      }
    }
  }
}

// ---------------- CSR build ----------------
__global__ __launch_bounds__(256) void zero_int_kernel(int* __restrict__ p, int n) {
  int i = blockIdx.x * 256 + threadIdx.x;
  if (i < n) p[i] = 0;
}

__global__ __launch_bounds__(256) void hist_kernel(const int* __restrict__ edge, int* __restrict__ counts, int E) {
  int e = blockIdx.x * 256 + threadIdx.x;
  if (e < E) atomicAdd(&counts[edge[(size_t)e * 2]], 1);
}

__global__ __launch_bounds__(1024) void scan_kernel(
    const int* __restrict__ counts, int* __restrict__ offsets, int* __restrict__ cursor, int n)
{
  __shared__ int sums[1024];
  const int t = threadIdx.x;
  const int per = (n + 1023) / 1024;
  const int lo = t * per, hi = min(lo + per, n);
  int s = 0;
  for (int i = lo; i < hi; i++) s += counts[i];
  sums[t] = s;
  __syncthreads();
  for (int off = 1; off < 1024; off <<= 1) {
    int v = sums[t];
    int u = (t >= off) ? sums[t - off] : 0;
    __syncthreads();
    sums[t] = v + u;
    __syncthreads();
  }
  int run = (t == 0) ? 0 : sums[t - 1];
  for (int i = lo; i < hi; i++) {
    offsets[i] = run;
    cursor[i] = run;
    run += counts[i];
  }
  if (t == 1023) offsets[n] = sums[1023];
}

__global__ __launch_bounds__(256) void scatter_ids_kernel(
    const int* __restrict__ edge, int* __restrict__ cursor, int* __restrict__ edge_list, int E)
{
  int e = blockIdx.x * 256 + threadIdx.x;
  if (e < E) {
    int d = edge[(size_t)e * 2];
    int p = atomicAdd(&cursor[d], 1);
    edge_list[p] = e;
  }
}

// ---------------- edge message (dst-sorted, bf16 streaming stores) ----------------
__global__ __launch_bounds__(256) void edge_msg_kernel(
    const float* __restrict__ so,
    const float* __restrict__ nv,
    const int*   __restrict__ edge,
    const float* __restrict__ diff,
    const float* __restrict__ dist,
    const float* __restrict__ rbf,
    const int*   __restrict__ edge_list,
    const float* __restrict__ w1, const float* __restrict__ b1, const float* __restrict__ a1p,
    const float* __restrict__ w2, const float* __restrict__ b2, const float* __restrict__ a2p,
    unsigned short* __restrict__ msg,   // [cap][512] bf16
    int p0, int p1)
{
  __shared__ float R_lds[TM][20];
  __shared__ float h_lds[TM][HD];
  __shared__ int   src_l[TM], eid_l[TM];
  __shared__ float unit_l[TM][3];

  const int t = threadIdx.x;
  const int tx = t & 31, ty = t >> 5;
  const int c4 = tx * 4;
  const int pblk = p0 + blockIdx.x * TM;
  const float a1 = a1p[0], a2 = a2p[0];

  if (t < TM) {
    int p = pblk + t;
    int e = (p < p1) ? edge_list[p] : -1;
    eid_l[t] = e;
    if (e >= 0) {
      src_l[t] = edge[(size_t)e * 2 + 1];
      float inv = 1.f / dist[e];
      unit_l[t][0] = diff[(size_t)e * 3 + 0] * inv;
      unit_l[t][1] = diff[(size_t)e * 3 + 1] * inv;
      unit_l[t][2] = diff[(size_t)e * 3 + 2] * inv;
    }
  }
  __syncthreads();

  for (int idx = t; idx < TM * 20; idx += 256) {
    int r = idx / 20, k = idx - r * 20;
    int e = eid_l[r];
    R_lds[r][k] = (e >= 0) ? rbf[(size_t)e * 20 + k] : 0.f;
  }
  __syncthreads();

  // layer 1 (K=20)
  {
    float acc[8][4];
    f32x4 bv = *(const f32x4*)&b1[c4];
    #pragma unroll
    for (int rr = 0; rr < 8; rr++)
      #pragma unroll
      for (int cc = 0; cc < 4; cc++) acc[rr][cc] = bv[cc];

    for (int k = 0; k < 20; k++) {
      f32x4 wv = *(const f32x4*)&w1[(size_t)k * HD + c4];
      #pragma unroll
      for (int rr = 0; rr < 8; rr++) {
        float av = R_lds[ty + 8 * rr][k];
        #pragma unroll
        for (int cc = 0; cc < 4; cc++) acc[rr][cc] += av * wv[cc];
      }
    }
    #pragma unroll
    for (int rr = 0; rr < 8; rr++) {
      f32x4 hv;
      #pragma unroll
      for (int cc = 0; cc < 4; cc++) hv[cc] = prelu_f(acc[rr][cc], a1);
      *(f32x4*)&h_lds[ty + 8 * rr][c4] = hv;
    }
  }
  __syncthreads();

  // layer 2: 3 gate planes
  float acc2[3][8][4];
  #pragma unroll
  for (int m = 0; m < 3; m++) {
    f32x4 bv = *(const f32x4*)&b2[m * HD + c4];
    #pragma unroll
    for (int rr = 0; rr < 8; rr++)
      #pragma unroll
      for (int cc = 0; cc < 4; cc++) acc2[m][rr][cc] = bv[cc];
  }
  for (int kg = 0; kg < HD / 4; kg++) {
    const int k = kg * 4;
    f32x4 av[8];
    #pragma unroll
    for (int rr = 0; rr < 8; rr++) av[rr] = *(const f32x4*)&h_lds[ty + 8 * rr][k];
    #pragma unroll
    for (int m = 0; m < 3; m++) {
      f32x4 wv[4];
      #pragma unroll
      for (int kk = 0; kk < 4; kk++)
        wv[kk] = *(const f32x4*)&w2[(size_t)(k + kk) * 384 + m * HD + c4];
      #pragma unroll
      for (int rr = 0; rr < 8; rr++)
        #pragma unroll
        for (int cc = 0; cc < 4; cc++)
          #pragma unroll
          for (int kk = 0; kk < 4; kk++)
            acc2[m][rr][cc] += av[rr][kk] * wv[kk][cc];
    }
  }

  // epilogue: gather + gate + bf16 streaming store (no atomics)
  #pragma unroll
  for (int rr = 0; rr < 8; rr++) {
    const int r = ty + 8 * rr;
    const int p = pblk + r;
    if (p >= p1) continue;
    const int src = src_l[r];
    const float u0 = unit_l[r][0], u1 = unit_l[r][1], u2 = unit_l[r][2];
    const size_t sb = (size_t)src * 384;
    f32x4 s0 = *(const f32x4*)&so[sb + c4];
    f32x4 s1 = *(const f32x4*)&so[sb + HD + c4];
    f32x4 s2 = *(const f32x4*)&so[sb + 2 * HD + c4];
    f32x4 gv, ms, ge;
    #pragma unroll
    for (int cc = 0; cc < 4; cc++) {
      gv[cc] = prelu_f(acc2[0][rr][cc], a2) * s0[cc];
      ms[cc] = prelu_f(acc2[1][rr][cc], a2) * s1[cc];
      ge[cc] = prelu_f(acc2[2][rr][cc], a2) * s2[cc];
    }
    unsigned short* mrow = msg + (size_t)(p - p0) * 512;
    ushort4 pk;
    pk.x = f2bf(ms[0]); pk.y = f2bf(ms[1]); pk.z = f2bf(ms[2]); pk.w = f2bf(ms[3]);
    *(ushort4*)&mrow[c4] = pk;
    #pragma unroll
    for (int d = 0; d < 3; d++) {
      f32x4 nvv = *(const f32x4*)&nv[((size_t)src * 3 + d) * HD + c4];
      const float ud = (d == 0) ? u0 : (d == 1) ? u1 : u2;
      f32x4 mv;
      #pragma unroll
      for (int cc = 0; cc < 4; cc++) mv[cc] = nvv[cc] * gv[cc] + ud * ge[cc];
      ushort4 pv;
      pv.x = f2bf(mv[0]); pv.y = f2bf(mv[1]); pv.z = f2bf(mv[2]); pv.w = f2bf(mv[3]);
      *(ushort4*)&mrow[(1 + d) * HD + c4] = pv;
    }
  }
}

// ---------------- per-node segment sum of messages ----------------
__global__ __launch_bounds__(256) void gather_kernel(
    const unsigned short* __restrict__ msg,
    const int* __restrict__ offsets,
    float* __restrict__ out, int N, int p0, int p1)
{
  const int node = blockIdx.x * 2 + (threadIdx.x >> 7);
  if (node >= N) return;
  const int t = threadIdx.x & 127;
  int s = offsets[node], e = offsets[node + 1];
  s = max(s, p0); e = min(e, p1);
  if (s >= e) return;
  const int j = t * 4;  // 4 consecutive of 512
  f32x4 acc = {0.f, 0.f, 0.f, 0.f};
  for (int p = s; p < e; p++) {
    ushort4 u = *(const ushort4*)&msg[(size_t)(p - p0) * 512 + j];
    acc[0] += bf2f(u.x); acc[1] += bf2f(u.y);
    acc[2] += bf2f(u.z); acc[3] += bf2f(u.w);
  }
  size_t o = (j < 128) ? ((size_t)node * HD + j)
                       : ((size_t)N * HD + ((size_t)node * 3 + (j >> 7) - 1) * HD + (j & 127));
  f32x4 cur = *(f32x4*)&out[o];
  cur += acc;
  *(f32x4*)&out[o] = cur;
}

// ---------------- fallback: atomic scatter (used only if ws too small) ----------------
__global__ __launch_bounds__(256) void edge_kernel(
    const float* __restrict__ so, const float* __restrict__ nv,
    const int* __restrict__ edge, const float* __restrict__ diff,
    const float* __restrict__ dist, const float* __restrict__ rbf,
    const float* __restrict__ w1, const float* __restrict__ b1, const float* __restrict__ a1p,
    const float* __restrict__ w2, const float* __restrict__ b2, const float* __restrict__ a2p,
    float* __restrict__ out_s, float* __restrict__ out_v, int E)
{
  __shared__ float R_lds[TM][20];
  __shared__ float h_lds[TM][HD];
  __shared__ int   src_l[TM], dst_l[TM];
  __shared__ float unit_l[TM][3];

  const int t = threadIdx.x;
  const int tx = t & 31, ty = t >> 5;
  const int c4 = tx * 4;
  const int e0 = blockIdx.x * TM;
  const float a1 = a1p[0], a2 = a2p[0];

  for (int idx = t; idx < TM * 20; idx += 256) {
    int r = idx / 20, k = idx - r * 20;
    int e = e0 + r;
    R_lds[r][k] = (e < E) ? rbf[(size_t)e * 20 + k] : 0.f;
  }
  if (t < TM) {
    int e = min(e0 + t, E - 1);
    src_l[t] = edge[(size_t)e * 2 + 1];
    dst_l[t] = edge[(size_t)e * 2 + 0];
    float inv = 1.f / dist[e];
    unit_l[t][0] = diff[(size_t)e * 3 + 0] * inv;
    unit_l[t][1] = diff[(size_t)e * 3 + 1] * inv;
    unit_l[t][2] = diff[(size_t)e * 3 + 2] * inv;
  }
  __syncthreads();

  {
    float acc[8][4];
    f32x4 bv = *(const f32x4*)&b1[c4];
    #pragma unroll
    for (int rr = 0; rr < 8; rr++)
      #pragma unroll
      for (int cc = 0; cc < 4; cc++) acc[rr][cc] = bv[cc];
    for (int k = 0; k < 20; k++) {
      f32x4 wv = *(const f32x4*)&w1[(size_t)k * HD + c4];
      #pragma unroll
      for (int rr = 0; rr < 8; rr++) {
        float av = R_lds[ty + 8 * rr][k];
        #pragma unroll
        for (int cc = 0; cc < 4; cc++) acc[rr][cc] += av * wv[cc];
      }
    }
    #pragma unroll
    for (int rr = 0; rr < 8; rr++) {
      f32x4 hv;
      #pragma unroll
      for (int cc = 0; cc < 4; cc++) hv[cc] = prelu_f(acc[rr][cc], a1);
      *(f32x4*)&h_lds[ty + 8 * rr][c4] = hv;
    }
  }
  __syncthreads();

  float acc2[3][8][4];
  #pragma unroll
  for (int m = 0; m < 3; m++) {
    f32x4 bv = *(const f32x4*)&b2[m * HD + c4];
    #pragma unroll
    for (int rr = 0; rr < 8; rr++)
      #pragma unroll
      for (int cc = 0; cc < 4; cc++) acc2[m][rr][cc] = bv[cc];
  }
  for (int kg = 0; kg < HD / 4; kg++) {
    const int k = kg * 4;
    f32x4 av[8];
    #pragma unroll
    for (int rr = 0; rr < 8; rr++) av[rr] = *(const f32x4*)&h_lds[ty + 8 * rr][k];
    #pragma unroll
    for (int m = 0; m < 3; m++) {
      f32x4 wv[4];
      #pragma unroll
      for (int kk = 0; kk < 4; kk++)
        wv[kk] = *(const f32x4*)&w2[(size_t)(k + kk) * 384 + m * HD + c4];
      #pragma unroll
      for (int rr = 0; rr < 8; rr++)
        #pragma unroll
        for (int cc = 0; cc < 4; cc++)
          #pragma unroll
          for (int kk = 0; kk < 4; kk++)
            acc2[m][rr][cc] += av[rr][kk] * wv[kk][cc];
    }
  }

  #pragma unroll
  for (int rr = 0; rr < 8; rr++) {
    const int r = ty + 8 * rr;
    const int e = e0 + r;
    if (e >= E) continue;
    const int src = src_l[r], dst = dst_l[r];
    const float u0 = unit_l[r][0], u1 = unit_l[r][1], u2 = unit_l[r][2];
    const size_t sb = (size_t)src * 384;
    f32x4 s0 = *(const f32x4*)&so[sb + c4];
    f32x4 s1 = *(const f32x4*)&so[sb + HD + c4];
    f32x4 s2 = *(const f32x4*)&so[sb + 2 * HD + c4];
    f32x4 gv, ms, ge;
    #pragma unroll
    for (int cc = 0; cc < 4; cc++) {
      gv[cc] = prelu_f(acc2[0][rr][cc], a2) * s0[cc];
      ms[cc] = prelu_f(acc2[1][rr][cc], a2) * s1[cc];
      ge[cc] = prelu_f(acc2[2][rr][cc], a2) * s2[cc];
    }
    float* osp = &out_s[(size_t)dst * HD + c4];
    #pragma unroll
    for (int cc = 0; cc < 4; cc++) atomicAdd(osp + cc, ms[cc]);
    #pragma unroll
    for (int d = 0; d < 3; d++) {
      f32x4 nvv = *(const f32x4*)&nv[((size_t)src * 3 + d) * HD + c4];
      const float ud = (d == 0) ? u0 : (d == 1) ? u1 : u2;
      float* ovp = &out_v[((size_t)dst * 3 + d) * HD + c4];
      #pragma unroll
      for (int cc = 0; cc < 4; cc++)
        atomicAdd(ovp + cc, nvv[cc] * gv[cc] + ud * ge[cc]);
    }
  }
}

extern "C" void kernel_launch(void* const* d_in, const int* in_sizes, int n_in,
                              void* d_out, int out_size, void* d_ws, size_t ws_size,
                              hipStream_t stream)
{
  const float* node_scalar = (const float*)d_in[0];
  const float* node_vector = (const float*)d_in[1];
  const int*   che_edge = (const int*)d_in[2];
  const float* che_diff = (const float*)d_in[3];
  const float* che_dist = (const float*)d_in[4];
  const float* che_rbf  = (const float*)d_in[5];
  const int*   vdw_edge = (const int*)d_in[6];
  const float* vdw_diff = (const float*)d_in[7];
  const float* vdw_dist = (const float*)d_in[8];
  const float* vdw_rbf  = (const float*)d_in[9];
  const float* mlp_p[24];
  for (int i = 0; i < 24; i++) mlp_p[i] = (const float*)d_in[10 + i];
  // mlp_p layout: [che_s 0..5][che_f 6..11][vdw_s 12..17][vdw_f 18..23]

  const int N = in_sizes[0] / HD;
  const int E_che = in_sizes[4];
  const int E_vdw = in_sizes[8];
  const int E_max = E_che > E_vdw ? E_che : E_vdw;

  // workspace layout
  char* wp = (char*)d_ws;
  size_t off = 0;
  float* so = (float*)(wp + off);      off += (size_t)N * 384 * 4;
  int* counts    = (int*)(wp + off);   off += (size_t)N * 4;
  int* offsets   = (int*)(wp + off);   off += (size_t)(N + 1) * 4;
  int* cursor    = (int*)(wp + off);   off += (size_t)N * 4;
  int* edge_list = (int*)(wp + off);   off += (size_t)E_max * 4;
  off = (off + 255) & ~(size_t)255;
  unsigned short* msg = (unsigned short*)(wp + off);
  size_t cap_edges = (ws_size > off) ? (ws_size - off) / 1024 : 0;  // 512 bf16 per edge

  float* out_s = (float*)d_out;
  float* out_v = out_s + (size_t)N * HD;

  const int n_ns4 = N * HD / 4;
  const int n_nv4 = N * 3 * HD / 4;
  init_out_kernel<<<2048, 256, 0, stream>>>(
      (const f32x4*)node_scalar, (const f32x4*)node_vector, (f32x4*)d_out, n_ns4, n_nv4);

  const bool use_csr = cap_edges >= 65536;

  for (int br = 0; br < 2; br++) {
    const int*   edge = br == 0 ? che_edge : vdw_edge;
    const float* diff = br == 0 ? che_diff : vdw_diff;
    const float* dist = br == 0 ? che_dist : vdw_dist;
    const float* rbf  = br == 0 ? che_rbf  : vdw_rbf;
    const int    E    = br == 0 ? E_che : E_vdw;
    const float* const* sp = &mlp_p[br == 0 ? 0 : 12];
    const float* const* fp = &mlp_p[br == 0 ? 6 : 18];

    node_mlp_kernel<<<(N + TM - 1) / TM, 256, 0, stream>>>(
        node_scalar, sp[0], sp[1], sp[2], sp[3], sp[4], sp[5], so, N);

    if (use_csr) {
      zero_int_kernel<<<(N + 255) / 256, 256, 0, stream>>>(counts, N);
      hist_kernel<<<(E + 255) / 256, 256, 0, stream>>>(edge, counts, E);
      scan_kernel<<<1, 1024, 0, stream>>>(counts, offsets, cursor, N);
      scatter_ids_kernel<<<(E + 255) / 256, 256, 0, stream>>>(edge, cursor, edge_list, E);

      int cap = (int)(cap_edges > (size_t)E ? (size_t)E : cap_edges);
      for (int p0 = 0; p0 < E; p0 += cap) {
        int p1 = p0 + cap < E ? p0 + cap : E;
        int nblk = (p1 - p0 + TM - 1) / TM;
        edge_msg_kernel<<<nblk, 256, 0, stream>>>(
            so, node_vector, edge, diff, dist, rbf, edge_list,
            fp[0], fp[1], fp[2], fp[3], fp[4], fp[5], msg, p0, p1);
        gather_kernel<<<(N + 1) / 2, 256, 0, stream>>>(msg, offsets, (float*)d_out, N, p0, p1);
      }
    } else {
      edge_kernel<<<(E + TM - 1) / TM, 256, 0, stream>>>(
          so, node_vector, edge, diff, dist, rbf,
          fp[0], fp[1], fp[2], fp[3], fp[4], fp[5], out_s, out_v, E);
    }
  }
}